// Round 17
// baseline (163.079 us; speedup 1.0000x reference)
//
#include <hip/hip_runtime.h>
#include <hip/hip_bf16.h>

typedef short bf16x8 __attribute__((ext_vector_type(8)));
typedef float f32x4  __attribute__((ext_vector_type(4)));
typedef unsigned int u32x4 __attribute__((ext_vector_type(4)));

#define LOG2E 1.44269504088896340736f

static __device__ __forceinline__ unsigned short f2bf(float f){
    __hip_bfloat16 h = __float2bfloat16(f);
    return __builtin_bit_cast(unsigned short, h);
}
static __device__ __forceinline__ unsigned pk_bf16(float lo, float hi){
    return (((unsigned)f2bf(hi)) << 16) | (unsigned)f2bf(lo);
}
static __device__ __forceinline__ float rcp_(float x){ return __builtin_amdgcn_rcpf(x); }
static __device__ __forceinline__ float ex2(float x){ return __builtin_amdgcn_exp2f(x); }
static __device__ __forceinline__ void lds_fence(){
    asm volatile("s_waitcnt lgkmcnt(0)" ::: "memory");
}
static __device__ __forceinline__ f32x4 mfma16(bf16x8 a, bf16x8 b, f32x4 c){
    return __builtin_amdgcn_mfma_f32_16x16x32_bf16(a, b, c, 0, 0, 0);
}

__global__ void marker_kernel(float* out, int n, float v){
    int i = blockIdx.x * 256 + threadIdx.x;
    if (i < n) out[i] = v;
}

// v3c: register-resident recurrence (v3, 137us) + chain surgery:
// the x-term MFMA (h-independent) for step t+1 is computed during step t,
// so the recurrence critical path is pack -> 8 h-MFMAs -> activations.
__global__ __launch_bounds__(256, 1)
void vae_mfma3c_kernel(const float* __restrict__ x,      const float* __restrict__ eps,
                       const float* __restrict__ eWih,   const float* __restrict__ eWhh,
                       const float* __restrict__ ebih,   const float* __restrict__ ebhh,
                       const float* __restrict__ Wmu,    const float* __restrict__ bmu,
                       const float* __restrict__ Wlv,    const float* __restrict__ blv,
                       const float* __restrict__ Wl2h,   const float* __restrict__ bl2h,
                       const float* __restrict__ Wl2h2,  const float* __restrict__ bl2h2,
                       const float* __restrict__ stok,   const float* __restrict__ Wemb,
                       const float* __restrict__ bemb,
                       const float* __restrict__ dWih,   const float* __restrict__ dWhh,
                       const float* __restrict__ dbih,   const float* __restrict__ dbhh,
                       const float* __restrict__ Wout,   const float* __restrict__ bout,
                       const float* __restrict__ Wseq,   const float* __restrict__ bseq,
                       const float* __restrict__ Wseq2,  const float* __restrict__ bseq2,
                       float* __restrict__ recon,
                       float* __restrict__ out_mu,
                       float* __restrict__ out_lv,
                       float* __restrict__ out_num)
{
    __shared__ float hbf[4][16][33];
    __shared__ float cbf[4][16][33];
    __shared__ float mubuf[4][16];
    __shared__ float x0buf[4][32];
    __shared__ float cw[524];
    // cw: 0 Wmu[64] | 64 Wlv[64] | 128 Wseq[32] | 160 bseq[32] | 192 Wseq2[32]
    //     224 Wl2h[32] | 256 bl2h[32] | 288 Wl2h2[32] | 320 bl2h2[32]
    //     352 Wout[160] | 512 bout[5] | 517 bmu | 518 blv | 519 bseq2

    const int tid = threadIdx.x;
    const int w   = tid >> 6;
    const int l   = tid & 63;
    const int c   = l & 15;     // batch row / A-fragment row
    const int g   = l >> 4;     // k-chunk / D row-group
    const int bbase = blockIdx.x * 64 + w * 16;

    if (tid < 64){ cw[tid] = Wmu[tid]; cw[64+tid] = Wlv[tid]; }
    if (tid < 32){
        cw[128+tid] = Wseq[tid];  cw[160+tid] = bseq[tid];  cw[192+tid] = Wseq2[tid];
        cw[224+tid] = Wl2h[tid];  cw[256+tid] = bl2h[tid];
        cw[288+tid] = Wl2h2[tid]; cw[320+tid] = bl2h2[tid];
    }
    if (tid < 160) cw[352+tid] = Wout[tid];
    if (tid < 5)   cw[512+tid] = bout[tid];
    if (tid == 0){ cw[517] = bmu[0]; cw[518] = blv[0]; cw[519] = bseq2[0]; }
    __syncthreads();

    // ---- encoder fragments: A = W with gate-row permutation, pre-scaled ----
    bf16x8 WH[8], WX[8];
    f32x4  biasv[8];
    #pragma unroll
    for (int n=0;n<8;++n){
        const int gt = n>>1, half = n&1;
        const float sc = (gt==2) ? (-2.0f*LOG2E) : (-LOG2E);
        const int GRc = gt*32 + ((c>>2)<<3) + half*4 + (c&3);
        bf16x8 t;
        #pragma unroll
        for (int j=0;j<8;++j) t[j] = (short)f2bf(sc * eWhh[(size_t)GRc*32 + g*8 + j]);
        WH[n] = t;
        bf16x8 tx = (bf16x8)0;
        if (g == 0){
            #pragma unroll
            for (int j=0;j<5;++j) tx[j] = (short)f2bf(sc * eWih[(size_t)GRc*5 + j]);
        }
        WX[n] = tx;
        f32x4 b4;
        #pragma unroll
        for (int q=0;q<4;++q){
            const int R = gt*32 + g*8 + half*4 + q;
            b4[q] = sc * (ebih[R] + ebhh[R]);
        }
        biasv[n] = b4;
    }

    float cs[8], hn[8];
    #pragma unroll
    for (int k=0;k<8;++k){ cs[k] = 0.0f; hn[k] = 0.0f; }
    u32x4 hpk = (u32x4)0;            // packed bf16 h: word i = units (g*8+2i, g*8+2i+1) of batch c

    // x(0) -> bx, prefetch x(1)
    float4 xA = {0,0,0,0}; float xB = 0.0f;
    bf16x8 bx = (bf16x8)0;
    if (g == 0){
        const float* xp = x + (size_t)(bbase+c)*500;
        xA = *(const float4*)xp; xB = xp[4];
        bx[0]=(short)f2bf(xA.x); bx[1]=(short)f2bf(xA.y);
        bx[2]=(short)f2bf(xA.z); bx[3]=(short)f2bf(xA.w);
        bx[4]=(short)f2bf(xB);
        xA = *(const float4*)(xp + 5); xB = xp[9];
    }
    f32x4 xacc[8];
    #pragma unroll
    for (int n=0;n<8;++n) xacc[n] = mfma16(WX[n], bx, biasv[n]);

    // ================= encoder LSTM (T=100), register-only recurrence =================
    for (int t=0; t<100; ++t){
        bf16x8 bh = __builtin_bit_cast(bf16x8, hpk);

        f32x4 acc[8];
        #pragma unroll
        for (int n=0;n<8;++n) acc[n] = mfma16(WH[n], bh, xacc[n]);

        // prepare next step's x-term while acc is in flight (h-independent)
        if (t < 99){
            bx = (bf16x8)0;
            if (g == 0){
                bx[0]=(short)f2bf(xA.x); bx[1]=(short)f2bf(xA.y);
                bx[2]=(short)f2bf(xA.z); bx[3]=(short)f2bf(xA.w);
                bx[4]=(short)f2bf(xB);
                if (t < 98){
                    const float* xp = x + (size_t)(bbase+c)*500 + (t+2)*5;
                    xA = *(const float4*)xp; xB = xp[4];
                }
            }
            #pragma unroll
            for (int n=0;n<8;++n) xacc[n] = mfma16(WX[n], bx, biasv[n]);
        }

        #pragma unroll
        for (int q=0;q<4;++q){
          #pragma unroll
          for (int u=0;u<2;++u){
            const int ul = u*4 + q;
            float ei = ex2(acc[0+u][q]);      // e^{-i}
            float ef = ex2(acc[2+u][q]);      // e^{-f}
            float eg = ex2(acc[4+u][q]);      // e^{-2g}
            float eo = ex2(acc[6+u][q]);      // e^{-o}
            float pig = (1.0f+ei)*(1.0f+eg);
            float num = cs[ul]*pig + (1.0f+ef)*(1.0f-eg);
            float cn  = num * rcp_((1.0f+ef)*pig);
            float ec  = ex2(cn * (-2.0f*LOG2E));
            hn[ul]    = (1.0f-ec) * rcp_((1.0f+eo)*(1.0f+ec));
            cs[ul]    = cn;
          }
        }
        hpk[0] = pk_bf16(hn[0], hn[1]);
        hpk[1] = pk_bf16(hn[2], hn[3]);
        hpk[2] = pk_bf16(hn[4], hn[5]);
        hpk[3] = pk_bf16(hn[6], hn[7]);
    }

    // ---- h_n / c_n to LDS for the heads (once) ----
    #pragma unroll
    for (int ul=0; ul<8; ++ul){
        hbf[w][c][g*8+ul] = hn[ul];
        cbf[w][c][g*8+ul] = cs[ul];
    }
    lds_fence();

    // ---- decoder fragments (loaded now; heads below hide latency) ----
    bf16x8 WI[8], WHd[8];
    f32x4  dbias[8];
    #pragma unroll
    for (int n=0;n<8;++n){
        const int gt = n>>1, half = n&1;
        const float sc = (gt==2) ? (-2.0f*LOG2E) : (-LOG2E);
        const int GRc = gt*32 + ((c>>2)<<3) + half*4 + (c&3);
        bf16x8 ti, th;
        #pragma unroll
        for (int j=0;j<8;++j){
            ti[j] = (short)f2bf(sc * dWih[(size_t)GRc*32 + g*8 + j]);
            th[j] = (short)f2bf(sc * dWhh[(size_t)GRc*32 + g*8 + j]);
        }
        WI[n] = ti; WHd[n] = th;
        f32x4 b4;
        #pragma unroll
        for (int q=0;q<4;++q){
            const int R = gt*32 + g*8 + half*4 + q;
            b4[q] = sc * (dbih[R] + dbhh[R]);
        }
        dbias[n] = b4;
    }
    bf16x8 WO = (bf16x8)0;
    f32x4 bosv = (f32x4)0;
    if (c < 5){
        bf16x8 to;
        #pragma unroll
        for (int j=0;j<8;++j) to[j] = (short)f2bf(Wout[c*32 + g*8 + j]);
        WO = to;
    }
    #pragma unroll
    for (int q=0;q<4;++q){
        const int dd = g*4 + q;
        bosv[q] = (dd < 5) ? bout[dd] : 0.0f;
    }

    // ---- heads: mu / logvar / num (lanes 0..15, one batch row each) ----
    if (l < 16){
        const int r = l;
        float mu = cw[517], lv = cw[518];
        #pragma unroll
        for (int k=0;k<32;++k){
            float hvv = hbf[w][r][k], cvv = cbf[w][r][k];
            mu += hvv*cw[k]    + cvv*cw[32+k];
            lv += hvv*cw[64+k] + cvv*cw[96+k];
        }
        out_mu[bbase+r] = mu;
        out_lv[bbase+r] = lv;
        mubuf[w][r] = mu;
        float z = mu + eps[bbase+r] * __builtin_amdgcn_exp2f(0.5f*LOG2E*lv);
        float a2 = cw[519];
        #pragma unroll
        for (int j=0;j<32;++j){
            float s = z*cw[128+j] + cw[160+j];
            s = s > 0.0f ? s : 0.01f*s;
            a2 += cw[192+j]*s;
        }
        out_num[bbase+r] = fmaxf(a2, 0.0f);
    }
    // x0 = relu(start_token @ Wemb^T + bemb), batch-independent
    if (l < 32){
        float v = bemb[l];
        #pragma unroll
        for (int d=0; d<5; ++d) v += stok[d]*Wemb[l*5 + d];
        x0buf[w][l] = fmaxf(v, 0.0f);
    }
    lds_fence();

    // ---- decoder init: h0/c0 = lrelu(mu*W + b) for units g*8+ul of batch c ----
    {
        const float muv = mubuf[w][c];
        #pragma unroll
        for (int ul=0; ul<8; ++ul){
            const int U = g*8 + ul;
            float a = muv*cw[224+U] + cw[256+U];
            float b = muv*cw[288+U] + cw[320+U];
            hn[ul] = (a > 0.0f ? a : 0.01f*a);
            cs[ul] = (b > 0.0f ? b : 0.01f*b);
        }
        hpk[0] = pk_bf16(hn[0], hn[1]);
        hpk[1] = pk_bf16(hn[2], hn[3]);
        hpk[2] = pk_bf16(hn[4], hn[5]);
        hpk[3] = pk_bf16(hn[6], hn[7]);
    }
    bf16x8 bx0;
    #pragma unroll
    for (int j=0;j<8;++j) bx0[j] = (short)f2bf(x0buf[w][g*8 + j]);

    // ================= decoder LSTM (T=100, autoregressive, register-only) =================
    #pragma unroll 2
    for (int t=0; t<100; ++t){
        bf16x8 bh = __builtin_bit_cast(bf16x8, hpk);

        if (t > 0){   // recon row t-1 = Wout @ h_t (D: row=dim g*4+q, col=batch c)
            f32x4 ao = mfma16(WO, bh, bosv);
            float* rp = recon + (size_t)(bbase+c)*500 + (t-1)*5;
            if (g == 0){ rp[0]=ao[0]; rp[1]=ao[1]; rp[2]=ao[2]; rp[3]=ao[3]; }
            else if (g == 1){ rp[4]=ao[0]; }
        }

        bf16x8 bx;
        if (t == 0) bx = bx0;
        else {
            u32x4 rv;
            #pragma unroll
            for (int i=0;i<4;++i){
                unsigned v = hpk[i];
                unsigned m = ((v >> 15) & 0x00010001u) * 0xFFFFu;
                rv[i] = v & ~m;          // relu on packed bf16 pairs
            }
            bx = __builtin_bit_cast(bf16x8, rv);
        }

        f32x4 acc[8];
        #pragma unroll
        for (int n=0;n<8;++n){
            f32x4 a = mfma16(WI[n], bx, dbias[n]);
            acc[n] = mfma16(WHd[n], bh, a);
        }

        #pragma unroll
        for (int q=0;q<4;++q){
          #pragma unroll
          for (int u=0;u<2;++u){
            const int ul = u*4 + q;
            float ei = ex2(acc[0+u][q]);
            float ef = ex2(acc[2+u][q]);
            float eg = ex2(acc[4+u][q]);
            float eo = ex2(acc[6+u][q]);
            float pig = (1.0f+ei)*(1.0f+eg);
            float num = cs[ul]*pig + (1.0f+ef)*(1.0f-eg);
            float cn  = num * rcp_((1.0f+ef)*pig);
            float ec  = ex2(cn * (-2.0f*LOG2E));
            hn[ul]    = (1.0f-ec) * rcp_((1.0f+eo)*(1.0f+ec));
            cs[ul]    = cn;
          }
        }
        hpk[0] = pk_bf16(hn[0], hn[1]);
        hpk[1] = pk_bf16(hn[2], hn[3]);
        hpk[2] = pk_bf16(hn[4], hn[5]);
        hpk[3] = pk_bf16(hn[6], hn[7]);
    }

    // final recon row 99 from h_100
    {
        bf16x8 bh = __builtin_bit_cast(bf16x8, hpk);
        f32x4 ao = mfma16(WO, bh, bosv);
        float* rp = recon + (size_t)(bbase+c)*500 + 99*5;
        if (g == 0){ rp[0]=ao[0]; rp[1]=ao[1]; rp[2]=ao[2]; rp[3]=ao[3]; }
        else if (g == 1){ rp[4]=ao[0]; }
    }
}

extern "C" void kernel_launch(void* const* d_in, const int* in_sizes, int n_in,
                              void* d_out, int out_size, void* d_ws, size_t ws_size,
                              hipStream_t stream)
{
    (void)d_ws; (void)ws_size;
    static const int EXPECT[27] = {8192000,16384,640,4096,128,128,64,1,64,1,
                                   32,32,32,32,5,160,32,4096,4096,128,128,
                                   160,5,32,32,32,1};
    bool in_ok = (n_in == 27);
    if (in_ok) for (int i = 0; i < 27; ++i) in_ok = in_ok && (in_sizes[i] == EXPECT[i]);
    bool out_ok = (out_size == 8241152);

    float* out = (float*)d_out;
    if (!in_ok){
        marker_kernel<<<(out_size + 255)/256, 256, 0, stream>>>(out, out_size, 2.0f);
        return;
    }
    if (!out_ok){
        marker_kernel<<<(out_size + 255)/256, 256, 0, stream>>>(out, out_size, 3.0f);
        return;
    }

    const float* x     = (const float*)d_in[0];
    const float* eps   = (const float*)d_in[1];
    const float* eWih  = (const float*)d_in[2];
    const float* eWhh  = (const float*)d_in[3];
    const float* ebih  = (const float*)d_in[4];
    const float* ebhh  = (const float*)d_in[5];
    const float* Wmu   = (const float*)d_in[6];
    const float* bmu   = (const float*)d_in[7];
    const float* Wlv   = (const float*)d_in[8];
    const float* blv   = (const float*)d_in[9];
    const float* Wl2h  = (const float*)d_in[10];
    const float* bl2h  = (const float*)d_in[11];
    const float* Wl2h2 = (const float*)d_in[12];
    const float* bl2h2 = (const float*)d_in[13];
    const float* stok  = (const float*)d_in[14];
    const float* Wemb  = (const float*)d_in[15];
    const float* bemb  = (const float*)d_in[16];
    const float* dWih  = (const float*)d_in[17];
    const float* dWhh  = (const float*)d_in[18];
    const float* dbih  = (const float*)d_in[19];
    const float* dbhh  = (const float*)d_in[20];
    const float* Wout  = (const float*)d_in[21];
    const float* bout  = (const float*)d_in[22];
    const float* Wseq  = (const float*)d_in[23];
    const float* bseq  = (const float*)d_in[24];
    const float* Wseq2 = (const float*)d_in[25];
    const float* bseq2 = (const float*)d_in[26];

    float* recon  = out;                 // [16384][100][5] f32
    float* out_mu = out + 8192000;       // [16384]
    float* out_lv = out_mu + 16384;      // [16384]
    float* out_nm = out_lv + 16384;      // [16384]

    vae_mfma3c_kernel<<<256, 256, 0, stream>>>(x, eps,
        eWih, eWhh, ebih, ebhh, Wmu, bmu, Wlv, blv,
        Wl2h, bl2h, Wl2h2, bl2h2, stok, Wemb, bemb,
        dWih, dWhh, dbih, dbhh, Wout, bout,
        Wseq, bseq, Wseq2, bseq2,
        recon, out_mu, out_lv, out_nm);
}

// Round 18
// 137.316 us; speedup vs baseline: 1.1876x; 1.1876x over previous
//
#include <hip/hip_runtime.h>
#include <hip/hip_bf16.h>

typedef short bf16x8 __attribute__((ext_vector_type(8)));
typedef float f32x4  __attribute__((ext_vector_type(4)));
typedef unsigned int u32x4 __attribute__((ext_vector_type(4)));

#define LOG2E 1.44269504088896340736f

static __device__ __forceinline__ unsigned short f2bf(float f){
    __hip_bfloat16 h = __float2bfloat16(f);
    return __builtin_bit_cast(unsigned short, h);
}
static __device__ __forceinline__ unsigned pk_bf16(float lo, float hi){
    return (((unsigned)f2bf(hi)) << 16) | (unsigned)f2bf(lo);
}
static __device__ __forceinline__ float rcp_(float x){ return __builtin_amdgcn_rcpf(x); }
static __device__ __forceinline__ float ex2(float x){ return __builtin_amdgcn_exp2f(x); }
static __device__ __forceinline__ void lds_fence(){
    asm volatile("s_waitcnt lgkmcnt(0)" ::: "memory");
}
static __device__ __forceinline__ f32x4 mfma16(bf16x8 a, bf16x8 b, f32x4 c){
    return __builtin_amdgcn_mfma_f32_16x16x32_bf16(a, b, c, 0, 0, 0);
}

__global__ void marker_kernel(float* out, int n, float v){
    int i = blockIdx.x * 256 + threadIdx.x;
    if (i < n) out[i] = v;
}

// v3 (best known, 137us): register-resident recurrence (zero in-loop LDS).
// A = WEIGHTS, B = h (cols = batch). Gate-row permutation GR(n,r) =
// gt*32 + (r>>2)*8 + (n&1)*4 + (r&3) makes lane (c,g) receive gates for
// units g*8..g*8+7 of batch c -- exactly its own B-fragment for the next
// step. h lives in 4 packed-bf16 VGPRs; no cross-lane traffic in the loop.
__global__ __launch_bounds__(256, 1)
void vae_mfma3_kernel(const float* __restrict__ x,      const float* __restrict__ eps,
                      const float* __restrict__ eWih,   const float* __restrict__ eWhh,
                      const float* __restrict__ ebih,   const float* __restrict__ ebhh,
                      const float* __restrict__ Wmu,    const float* __restrict__ bmu,
                      const float* __restrict__ Wlv,    const float* __restrict__ blv,
                      const float* __restrict__ Wl2h,   const float* __restrict__ bl2h,
                      const float* __restrict__ Wl2h2,  const float* __restrict__ bl2h2,
                      const float* __restrict__ stok,   const float* __restrict__ Wemb,
                      const float* __restrict__ bemb,
                      const float* __restrict__ dWih,   const float* __restrict__ dWhh,
                      const float* __restrict__ dbih,   const float* __restrict__ dbhh,
                      const float* __restrict__ Wout,   const float* __restrict__ bout,
                      const float* __restrict__ Wseq,   const float* __restrict__ bseq,
                      const float* __restrict__ Wseq2,  const float* __restrict__ bseq2,
                      float* __restrict__ recon,
                      float* __restrict__ out_mu,
                      float* __restrict__ out_lv,
                      float* __restrict__ out_num)
{
    __shared__ float hbf[4][16][33];   // f32 h_n for heads (once)
    __shared__ float cbf[4][16][33];   // f32 c_n for heads (once)
    __shared__ float mubuf[4][16];
    __shared__ float x0buf[4][32];
    __shared__ float cw[524];
    // cw: 0 Wmu[64] | 64 Wlv[64] | 128 Wseq[32] | 160 bseq[32] | 192 Wseq2[32]
    //     224 Wl2h[32] | 256 bl2h[32] | 288 Wl2h2[32] | 320 bl2h2[32]
    //     352 Wout[160] | 512 bout[5] | 517 bmu | 518 blv | 519 bseq2

    const int tid = threadIdx.x;
    const int w   = tid >> 6;
    const int l   = tid & 63;
    const int c   = l & 15;     // batch row / A-fragment row
    const int g   = l >> 4;     // k-chunk / D row-group
    const int bbase = blockIdx.x * 64 + w * 16;

    if (tid < 64){ cw[tid] = Wmu[tid]; cw[64+tid] = Wlv[tid]; }
    if (tid < 32){
        cw[128+tid] = Wseq[tid];  cw[160+tid] = bseq[tid];  cw[192+tid] = Wseq2[tid];
        cw[224+tid] = Wl2h[tid];  cw[256+tid] = bl2h[tid];
        cw[288+tid] = Wl2h2[tid]; cw[320+tid] = bl2h2[tid];
    }
    if (tid < 160) cw[352+tid] = Wout[tid];
    if (tid < 5)   cw[512+tid] = bout[tid];
    if (tid == 0){ cw[517] = bmu[0]; cw[518] = blv[0]; cw[519] = bseq2[0]; }
    __syncthreads();

    // ---- encoder fragments: A = W with gate-row permutation, pre-scaled ----
    bf16x8 WH[8], WX[8];
    f32x4  biasv[8];
    #pragma unroll
    for (int n=0;n<8;++n){
        const int gt = n>>1, half = n&1;
        const float sc = (gt==2) ? (-2.0f*LOG2E) : (-LOG2E);
        const int GRc = gt*32 + ((c>>2)<<3) + half*4 + (c&3);
        bf16x8 t;
        #pragma unroll
        for (int j=0;j<8;++j) t[j] = (short)f2bf(sc * eWhh[(size_t)GRc*32 + g*8 + j]);
        WH[n] = t;
        bf16x8 tx = (bf16x8)0;
        if (g == 0){
            #pragma unroll
            for (int j=0;j<5;++j) tx[j] = (short)f2bf(sc * eWih[(size_t)GRc*5 + j]);
        }
        WX[n] = tx;
        f32x4 b4;
        #pragma unroll
        for (int q=0;q<4;++q){
            const int R = gt*32 + g*8 + half*4 + q;
            b4[q] = sc * (ebih[R] + ebhh[R]);
        }
        biasv[n] = b4;
    }

    float cs[8], hn[8];
    #pragma unroll
    for (int k=0;k<8;++k){ cs[k] = 0.0f; hn[k] = 0.0f; }
    u32x4 hpk = (u32x4)0;            // packed bf16 h: word i = units (g*8+2i, g*8+2i+1) of batch c

    float4 xA = {0,0,0,0}; float xB = 0.0f;
    if (g == 0){
        const float* xp = x + (size_t)(bbase+c)*500;
        xA = *(const float4*)xp; xB = xp[4];
    }

    // ================= encoder LSTM (T=100), register-only recurrence =================
    for (int t=0; t<100; ++t){
        bf16x8 bx = (bf16x8)0;
        if (g == 0){
            bx[0]=(short)f2bf(xA.x); bx[1]=(short)f2bf(xA.y);
            bx[2]=(short)f2bf(xA.z); bx[3]=(short)f2bf(xA.w);
            bx[4]=(short)f2bf(xB);
            if (t < 99){
                const float* xp = x + (size_t)(bbase+c)*500 + (t+1)*5;
                xA = *(const float4*)xp; xB = xp[4];
            }
        }
        bf16x8 bh = __builtin_bit_cast(bf16x8, hpk);

        f32x4 acc[8];
        #pragma unroll
        for (int n=0;n<8;++n){
            f32x4 a = mfma16(WX[n], bx, biasv[n]);
            acc[n] = mfma16(WH[n], bh, a);
        }

        #pragma unroll
        for (int q=0;q<4;++q){
          #pragma unroll
          for (int u=0;u<2;++u){
            const int ul = u*4 + q;
            float ei = ex2(acc[0+u][q]);      // e^{-i}
            float ef = ex2(acc[2+u][q]);      // e^{-f}
            float eg = ex2(acc[4+u][q]);      // e^{-2g}
            float eo = ex2(acc[6+u][q]);      // e^{-o}
            float pig = (1.0f+ei)*(1.0f+eg);
            float num = cs[ul]*pig + (1.0f+ef)*(1.0f-eg);
            float cn  = num * rcp_((1.0f+ef)*pig);
            float ec  = ex2(cn * (-2.0f*LOG2E));
            hn[ul]    = (1.0f-ec) * rcp_((1.0f+eo)*(1.0f+ec));
            cs[ul]    = cn;
          }
        }
        hpk[0] = pk_bf16(hn[0], hn[1]);
        hpk[1] = pk_bf16(hn[2], hn[3]);
        hpk[2] = pk_bf16(hn[4], hn[5]);
        hpk[3] = pk_bf16(hn[6], hn[7]);
    }

    // ---- h_n / c_n to LDS for the heads (once) ----
    #pragma unroll
    for (int ul=0; ul<8; ++ul){
        hbf[w][c][g*8+ul] = hn[ul];
        cbf[w][c][g*8+ul] = cs[ul];
    }
    lds_fence();

    // ---- decoder fragments (loaded now; heads below hide latency) ----
    bf16x8 WI[8], WHd[8];
    f32x4  dbias[8];
    #pragma unroll
    for (int n=0;n<8;++n){
        const int gt = n>>1, half = n&1;
        const float sc = (gt==2) ? (-2.0f*LOG2E) : (-LOG2E);
        const int GRc = gt*32 + ((c>>2)<<3) + half*4 + (c&3);
        bf16x8 ti, th;
        #pragma unroll
        for (int j=0;j<8;++j){
            ti[j] = (short)f2bf(sc * dWih[(size_t)GRc*32 + g*8 + j]);
            th[j] = (short)f2bf(sc * dWhh[(size_t)GRc*32 + g*8 + j]);
        }
        WI[n] = ti; WHd[n] = th;
        f32x4 b4;
        #pragma unroll
        for (int q=0;q<4;++q){
            const int R = gt*32 + g*8 + half*4 + q;
            b4[q] = sc * (dbih[R] + dbhh[R]);
        }
        dbias[n] = b4;
    }
    bf16x8 WO = (bf16x8)0;
    f32x4 bosv = (f32x4)0;
    if (c < 5){
        bf16x8 to;
        #pragma unroll
        for (int j=0;j<8;++j) to[j] = (short)f2bf(Wout[c*32 + g*8 + j]);
        WO = to;
    }
    #pragma unroll
    for (int q=0;q<4;++q){
        const int dd = g*4 + q;
        bosv[q] = (dd < 5) ? bout[dd] : 0.0f;
    }

    // ---- heads: mu / logvar / num (lanes 0..15, one batch row each) ----
    if (l < 16){
        const int r = l;
        float mu = cw[517], lv = cw[518];
        #pragma unroll
        for (int k=0;k<32;++k){
            float hvv = hbf[w][r][k], cvv = cbf[w][r][k];
            mu += hvv*cw[k]    + cvv*cw[32+k];
            lv += hvv*cw[64+k] + cvv*cw[96+k];
        }
        out_mu[bbase+r] = mu;
        out_lv[bbase+r] = lv;
        mubuf[w][r] = mu;
        float z = mu + eps[bbase+r] * __builtin_amdgcn_exp2f(0.5f*LOG2E*lv);
        float a2 = cw[519];
        #pragma unroll
        for (int j=0;j<32;++j){
            float s = z*cw[128+j] + cw[160+j];
            s = s > 0.0f ? s : 0.01f*s;
            a2 += cw[192+j]*s;
        }
        out_num[bbase+r] = fmaxf(a2, 0.0f);
    }
    // x0 = relu(start_token @ Wemb^T + bemb), batch-independent
    if (l < 32){
        float v = bemb[l];
        #pragma unroll
        for (int d=0; d<5; ++d) v += stok[d]*Wemb[l*5 + d];
        x0buf[w][l] = fmaxf(v, 0.0f);
    }
    lds_fence();

    // ---- decoder init: h0/c0 = lrelu(mu*W + b) for units g*8+ul of batch c ----
    {
        const float muv = mubuf[w][c];
        #pragma unroll
        for (int ul=0; ul<8; ++ul){
            const int U = g*8 + ul;
            float a = muv*cw[224+U] + cw[256+U];
            float b = muv*cw[288+U] + cw[320+U];
            hn[ul] = (a > 0.0f ? a : 0.01f*a);
            cs[ul] = (b > 0.0f ? b : 0.01f*b);
        }
        hpk[0] = pk_bf16(hn[0], hn[1]);
        hpk[1] = pk_bf16(hn[2], hn[3]);
        hpk[2] = pk_bf16(hn[4], hn[5]);
        hpk[3] = pk_bf16(hn[6], hn[7]);
    }
    bf16x8 bx0;
    #pragma unroll
    for (int j=0;j<8;++j) bx0[j] = (short)f2bf(x0buf[w][g*8 + j]);

    // ================= decoder LSTM (T=100, autoregressive, register-only) =================
    for (int t=0; t<100; ++t){
        bf16x8 bh = __builtin_bit_cast(bf16x8, hpk);

        if (t > 0){   // recon row t-1 = Wout @ h_t (D: row=dim g*4+q, col=batch c)
            f32x4 ao = mfma16(WO, bh, bosv);
            float* rp = recon + (size_t)(bbase+c)*500 + (t-1)*5;
            if (g == 0){ rp[0]=ao[0]; rp[1]=ao[1]; rp[2]=ao[2]; rp[3]=ao[3]; }
            else if (g == 1){ rp[4]=ao[0]; }
        }

        bf16x8 bx;
        if (t == 0) bx = bx0;
        else {
            u32x4 rv;
            #pragma unroll
            for (int i=0;i<4;++i){
                unsigned v = hpk[i];
                unsigned m = ((v >> 15) & 0x00010001u) * 0xFFFFu;
                rv[i] = v & ~m;          // relu on packed bf16 pairs
            }
            bx = __builtin_bit_cast(bf16x8, rv);
        }

        f32x4 acc[8];
        #pragma unroll
        for (int n=0;n<8;++n){
            f32x4 a = mfma16(WI[n], bx, dbias[n]);
            acc[n] = mfma16(WHd[n], bh, a);
        }

        #pragma unroll
        for (int q=0;q<4;++q){
          #pragma unroll
          for (int u=0;u<2;++u){
            const int ul = u*4 + q;
            float ei = ex2(acc[0+u][q]);
            float ef = ex2(acc[2+u][q]);
            float eg = ex2(acc[4+u][q]);
            float eo = ex2(acc[6+u][q]);
            float pig = (1.0f+ei)*(1.0f+eg);
            float num = cs[ul]*pig + (1.0f+ef)*(1.0f-eg);
            float cn  = num * rcp_((1.0f+ef)*pig);
            float ec  = ex2(cn * (-2.0f*LOG2E));
            hn[ul]    = (1.0f-ec) * rcp_((1.0f+eo)*(1.0f+ec));
            cs[ul]    = cn;
          }
        }
        hpk[0] = pk_bf16(hn[0], hn[1]);
        hpk[1] = pk_bf16(hn[2], hn[3]);
        hpk[2] = pk_bf16(hn[4], hn[5]);
        hpk[3] = pk_bf16(hn[6], hn[7]);
    }

    // final recon row 99 from h_100
    {
        bf16x8 bh = __builtin_bit_cast(bf16x8, hpk);
        f32x4 ao = mfma16(WO, bh, bosv);
        float* rp = recon + (size_t)(bbase+c)*500 + 99*5;
        if (g == 0){ rp[0]=ao[0]; rp[1]=ao[1]; rp[2]=ao[2]; rp[3]=ao[3]; }
        else if (g == 1){ rp[4]=ao[0]; }
    }
}

extern "C" void kernel_launch(void* const* d_in, const int* in_sizes, int n_in,
                              void* d_out, int out_size, void* d_ws, size_t ws_size,
                              hipStream_t stream)
{
    (void)d_ws; (void)ws_size;
    static const int EXPECT[27] = {8192000,16384,640,4096,128,128,64,1,64,1,
                                   32,32,32,32,5,160,32,4096,4096,128,128,
                                   160,5,32,32,32,1};
    bool in_ok = (n_in == 27);
    if (in_ok) for (int i = 0; i < 27; ++i) in_ok = in_ok && (in_sizes[i] == EXPECT[i]);
    bool out_ok = (out_size == 8241152);

    float* out = (float*)d_out;
    if (!in_ok){
        marker_kernel<<<(out_size + 255)/256, 256, 0, stream>>>(out, out_size, 2.0f);
        return;
    }
    if (!out_ok){
        marker_kernel<<<(out_size + 255)/256, 256, 0, stream>>>(out, out_size, 3.0f);
        return;
    }

    const float* x     = (const float*)d_in[0];
    const float* eps   = (const float*)d_in[1];
    const float* eWih  = (const float*)d_in[2];
    const float* eWhh  = (const float*)d_in[3];
    const float* ebih  = (const float*)d_in[4];
    const float* ebhh  = (const float*)d_in[5];
    const float* Wmu   = (const float*)d_in[6];
    const float* bmu   = (const float*)d_in[7];
    const float* Wlv   = (const float*)d_in[8];
    const float* blv   = (const float*)d_in[9];
    const float* Wl2h  = (const float*)d_in[10];
    const float* bl2h  = (const float*)d_in[11];
    const float* Wl2h2 = (const float*)d_in[12];
    const float* bl2h2 = (const float*)d_in[13];
    const float* stok  = (const float*)d_in[14];
    const float* Wemb  = (const float*)d_in[15];
    const float* bemb  = (const float*)d_in[16];
    const float* dWih  = (const float*)d_in[17];
    const float* dWhh  = (const float*)d_in[18];
    const float* dbih  = (const float*)d_in[19];
    const float* dbhh  = (const float*)d_in[20];
    const float* Wout  = (const float*)d_in[21];
    const float* bout  = (const float*)d_in[22];
    const float* Wseq  = (const float*)d_in[23];
    const float* bseq  = (const float*)d_in[24];
    const float* Wseq2 = (const float*)d_in[25];
    const float* bseq2 = (const float*)d_in[26];

    float* recon  = out;                 // [16384][100][5] f32
    float* out_mu = out + 8192000;       // [16384]
    float* out_lv = out_mu + 16384;      // [16384]
    float* out_nm = out_lv + 16384;      // [16384]

    vae_mfma3_kernel<<<256, 256, 0, stream>>>(x, eps,
        eWih, eWhh, ebih, ebhh, Wmu, bmu, Wlv, blv,
        Wl2h, bl2h, Wl2h2, bl2h2, stok, Wemb, bemb,
        dWih, dWhh, dbih, dbhh, Wout, bout,
        Wseq, bseq, Wseq2, bseq2,
        recon, out_mu, out_lv, out_nm);
}